// Round 7
// baseline (10117.735 us; speedup 1.0000x reference)
//
#include <hip/hip_runtime.h>
#include <stdint.h>

#define T_LEN 4096
#define NVOC 256
#define EMBD 512
#define HID 512
#define G4 2048
#define NEGV (-10000.0f)
#define START_TAG 0
#define STOP_TAG 1

typedef float f4 __attribute__((ext_vector_type(4)));

// raw workgroup barrier: wait LDS ops only (no vmcnt drain)
#define BAR_LGKM() do { \
    asm volatile("s_waitcnt lgkmcnt(0)\n\ts_barrier" ::: "memory"); \
    __builtin_amdgcn_sched_barrier(0); \
} while (0)

// ---------------- generic C[M,N] = A[M,K] @ B[N,K]^T + bias0 + bias1 ----------------
__global__ __launch_bounds__(256) void gemm_abt(
    const float* __restrict__ A, const float* __restrict__ B,
    const float* __restrict__ bias0, const float* __restrict__ bias1,
    float* __restrict__ C, int M, int N, int K)
{
    __shared__ float As[16][65];
    __shared__ float Bs[16][65];
    int m0 = blockIdx.x * 64, n0 = blockIdx.y * 64;
    int tid = threadIdx.x;
    int lr = tid >> 2;
    int lk = (tid & 3) << 2;
    int tr = tid & 15, tc = tid >> 4;
    float acc[4][4] = {};
    for (int k0 = 0; k0 < K; k0 += 16) {
        float4 av = *(const float4*)(A + (size_t)(m0 + lr) * K + k0 + lk);
        float4 bv = *(const float4*)(B + (size_t)(n0 + lr) * K + k0 + lk);
        As[lk + 0][lr] = av.x; As[lk + 1][lr] = av.y; As[lk + 2][lr] = av.z; As[lk + 3][lr] = av.w;
        Bs[lk + 0][lr] = bv.x; Bs[lk + 1][lr] = bv.y; Bs[lk + 2][lr] = bv.z; Bs[lk + 3][lr] = bv.w;
        __syncthreads();
#pragma unroll
        for (int kk = 0; kk < 16; ++kk) {
            float a[4], b[4];
#pragma unroll
            for (int x = 0; x < 4; ++x) a[x] = As[kk][tr * 4 + x];
#pragma unroll
            for (int y = 0; y < 4; ++y) b[y] = Bs[kk][tc * 4 + y];
#pragma unroll
            for (int y = 0; y < 4; ++y)
#pragma unroll
                for (int x = 0; x < 4; ++x)
                    acc[y][x] += a[x] * b[y];
        }
        __syncthreads();
    }
#pragma unroll
    for (int y = 0; y < 4; ++y) {
        int n = n0 + tc * 4 + y;
        float bb = bias0 ? bias0[n] : 0.f;
        if (bias1) bb += bias1[n];
#pragma unroll
        for (int x = 0; x < 4; ++x)
            C[(size_t)(m0 + tr * 4 + x) * N + n] = acc[y][x] + bb;
    }
}

__device__ __forceinline__ float fast_sig(float x) {
    return __builtin_amdgcn_rcpf(1.f + __expf(-x));
}
__device__ __forceinline__ float fast_tanh(float x) {
    return 2.f * __builtin_amdgcn_rcpf(1.f + __expf(-2.f * x)) - 1.f;
}

// ---------------- persistent BiLSTM ----------------
// 64 blocks x 512 threads. blocks 0..31: forward, 32..63: backward.
// thread map: q = tid&7 (64-col eighth), g = (tid>>3)&3 (gate), u = tid>>5 (unit).
// Weights: 16 NAMED f4 (no array -> no stack slot), pinned opaque -> resident.
// PE: 1-step-ahead register prefetch (src 2 ahead) -> HBM latency off the path.
// h exchange: tagged u64 words, relaxed agent atomics (fence-free), 2-slot rotation.
__global__ __launch_bounds__(512, 1) void lstm_kernel(
    const int* __restrict__ src,
    const float* __restrict__ PE_f, const float* __restrict__ PE_b,
    const float* __restrict__ Whh_f, const float* __restrict__ Whh_b,
    float* __restrict__ H, unsigned long long* __restrict__ pub)
{
    int wg  = blockIdx.x & 31;
    int dir = blockIdx.x >> 5;          // 0 = fwd, 1 = bwd
    const float* PE  = dir ? PE_b : PE_f;
    const float* Whh = dir ? Whh_b : Whh_f;
    unsigned long long* mypub = pub + (size_t)dir * 1024;   // [slot][512]

    int tid = threadIdx.x;
    int q = tid & 7;                    // column eighth (64 cols)
    int g = (tid >> 3) & 3;             // gate 0..3 (i,f,g,o)
    int u = tid >> 5;                   // unit 0..15
    int hu0 = wg * 16;
    int grow = g * 512 + hu0 + u;       // gate row in W_hh (== PE column)

    // weights -> 16 NAMED registers, pinned (opaque origin: no remat, no slot)
    const f4* wsrc = (const f4*)(Whh + (size_t)grow * 512 + q * 64);
    f4 w00 = wsrc[0],  w01 = wsrc[1],  w02 = wsrc[2],  w03 = wsrc[3];
    f4 w04 = wsrc[4],  w05 = wsrc[5],  w06 = wsrc[6],  w07 = wsrc[7];
    f4 w08 = wsrc[8],  w09 = wsrc[9],  w10 = wsrc[10], w11 = wsrc[11];
    f4 w12 = wsrc[12], w13 = wsrc[13], w14 = wsrc[14], w15 = wsrc[15];
    asm volatile("" : "+v"(w00), "+v"(w01), "+v"(w02), "+v"(w03),
                      "+v"(w04), "+v"(w05), "+v"(w06), "+v"(w07),
                      "+v"(w08), "+v"(w09), "+v"(w10), "+v"(w11),
                      "+v"(w12), "+v"(w13), "+v"(w14), "+v"(w15));

    // double-buffered; row stride 68 floats -> the 8 q-streams hit disjoint banks
    __shared__ __align__(16) float h_sh[2][8][68];
    float c_state = 0.f;                // valid in leader lanes
    bool leader = ((tid & 31) == 0);
    bool q0 = (q == 0);

    // PE software pipeline: pe_cur for step 0, st_nxt for step 1
    int st_nxt = src[dir ? (T_LEN - 2) : 1];
    float pe_cur = 0.f;
    if (q0) {
        int st0 = src[dir ? (T_LEN - 1) : 0];
        pe_cur = PE[(size_t)st0 * G4 + grow];
    }

    for (int s = 0; s < T_LEN; ++s) {
        int par = s & 1;
        int t = dir ? (T_LEN - 1 - s) : s;

        // issue step-(s+1) PE load and step-(s+2) src load (latency covered by a full step)
        float pe_nxt = 0.f;
        if (q0) pe_nxt = PE[(size_t)st_nxt * G4 + grow];
        int s2 = (s + 2 < T_LEN) ? (s + 2) : (T_LEN - 1);
        int st_n2 = src[dir ? (T_LEN - 1 - s2) : s2];

        if (s == 0) {
            h_sh[0][tid >> 6][tid & 63] = 0.f;
        } else {
            unsigned long long* p0 = mypub + (size_t)((s - 1) & 1) * 512 + tid;
            unsigned int want = (unsigned)s;
            unsigned long long w0 = __hip_atomic_load(p0, __ATOMIC_RELAXED, __HIP_MEMORY_SCOPE_AGENT);
            while ((unsigned)(w0 >> 32) < want) {
                __builtin_amdgcn_s_sleep(1);
                w0 = __hip_atomic_load(p0, __ATOMIC_RELAXED, __HIP_MEMORY_SCOPE_AGENT);
            }
            float f0; __builtin_memcpy(&f0, &w0, 4);
            h_sh[par][tid >> 6][tid & 63] = f0;
        }
        BAR_LGKM();                      // h_sh[par] ready (no vmcnt drain)

        // 64-wide partial dot, packed f32x2 FMAs
        const f4* hq = (const f4*)(&h_sh[par][q][0]);
        f4 acc = {0.f, 0.f, 0.f, 0.f};
#define ACC(W,J) { f4 hv = hq[J]; acc += W * hv; }
        ACC(w00,0)  ACC(w01,1)  ACC(w02,2)  ACC(w03,3)
        ACC(w04,4)  ACC(w05,5)  ACC(w06,6)  ACC(w07,7)
        ACC(w08,8)  ACC(w09,9)  ACC(w10,10) ACC(w11,11)
        ACC(w12,12) ACC(w13,13) ACC(w14,14) ACC(w15,15)
#undef ACC
        float dot = (acc.x + acc.y) + (acc.z + acc.w);
        dot += __shfl_xor(dot, 1);
        dot += __shfl_xor(dot, 2);
        dot += __shfl_xor(dot, 4);       // q==0 lanes hold full gate dot
        float val = dot + pe_cur;        // gate pre-activation (q==0 lanes)
        int base = tid & ~31;
        float vf = __shfl(val, base + 8);
        float vg = __shfl(val, base + 16);
        float vo = __shfl(val, base + 24);
        if (leader) {                    // leader lane has gate i (g==0)
            float si = fast_sig(val);
            float sf = fast_sig(vf);
            float tg = fast_tanh(vg);
            float so = fast_sig(vo);
            c_state = sf * c_state + si * tg;
            float hval = so * fast_tanh(c_state);
            unsigned int hb; __builtin_memcpy(&hb, &hval, 4);
            unsigned long long wv = ((unsigned long long)(unsigned)(s + 1) << 32) | (unsigned long long)hb;
            __hip_atomic_store(mypub + (size_t)par * 512 + hu0 + u, wv,
                               __ATOMIC_RELAXED, __HIP_MEMORY_SCOPE_AGENT);
            H[(size_t)t * 1024 + dir * 512 + hu0 + u] = hval;
        }
        pe_cur = pe_nxt;                 // rotate software pipeline
        st_nxt = st_n2;
        // next step writes h_sh[par^1]; 2-slot rotation + all-to-all tag coupling
        // bounds skew (overwrite of slot X gated on all WGs having consumed X).
    }
}

// ---------------- Viterbi forward: 512 thr, named-resident trans, pk max ----------------
__global__ __launch_bounds__(512, 1) void viterbi_fwd_kernel(
    const float* __restrict__ feats, const float* __restrict__ trans,
    float* __restrict__ fv_all)
{
    __shared__ __align__(16) float fvb[2][256];
    int tid = threadIdx.x;
    int wv = tid >> 6;           // wave 0..7
    int l  = tid & 63;
    int h  = l >> 5;             // i-half 0/1
    int jj = l & 31;
    int j  = wv * 32 + jj;       // output tag
    const f4* tr = (const f4*)(trans + (size_t)j * 256 + h * 128);
    f4 T00 = tr[0],  T01 = tr[1],  T02 = tr[2],  T03 = tr[3];
    f4 T04 = tr[4],  T05 = tr[5],  T06 = tr[6],  T07 = tr[7];
    f4 T08 = tr[8],  T09 = tr[9],  T10 = tr[10], T11 = tr[11];
    f4 T12 = tr[12], T13 = tr[13], T14 = tr[14], T15 = tr[15];
    f4 T16 = tr[16], T17 = tr[17], T18 = tr[18], T19 = tr[19];
    f4 T20 = tr[20], T21 = tr[21], T22 = tr[22], T23 = tr[23];
    f4 T24 = tr[24], T25 = tr[25], T26 = tr[26], T27 = tr[27];
    f4 T28 = tr[28], T29 = tr[29], T30 = tr[30], T31 = tr[31];
    asm volatile("" : "+v"(T00), "+v"(T01), "+v"(T02), "+v"(T03),
                      "+v"(T04), "+v"(T05), "+v"(T06), "+v"(T07),
                      "+v"(T08), "+v"(T09), "+v"(T10), "+v"(T11),
                      "+v"(T12), "+v"(T13), "+v"(T14), "+v"(T15));
    asm volatile("" : "+v"(T16), "+v"(T17), "+v"(T18), "+v"(T19),
                      "+v"(T20), "+v"(T21), "+v"(T22), "+v"(T23),
                      "+v"(T24), "+v"(T25), "+v"(T26), "+v"(T27),
                      "+v"(T28), "+v"(T29), "+v"(T30), "+v"(T31));
    if (tid < 256) fvb[0][tid] = (tid == START_TAG) ? 0.f : NEGV;
    bool h0 = (h == 0);
    float ft_next = h0 ? feats[j] : 0.f;
    __syncthreads();
    for (int t = 0; t < T_LEN; ++t) {
        int p = t & 1;
        float ft = ft_next;
        if (h0 && t + 1 < T_LEN) ft_next = feats[(size_t)(t + 1) * 256 + j];
        const f4* fq = (const f4*)(&fvb[p][h * 128]);   // wave-broadcast reads
        f4 mv = {-1e30f, -1e30f, -1e30f, -1e30f};
#define VSTEP(W,K) { f4 sv = fq[K] + W; mv = __builtin_elementwise_max(mv, sv); }
        VSTEP(T00,0)  VSTEP(T01,1)  VSTEP(T02,2)  VSTEP(T03,3)
        VSTEP(T04,4)  VSTEP(T05,5)  VSTEP(T06,6)  VSTEP(T07,7)
        VSTEP(T08,8)  VSTEP(T09,9)  VSTEP(T10,10) VSTEP(T11,11)
        VSTEP(T12,12) VSTEP(T13,13) VSTEP(T14,14) VSTEP(T15,15)
        VSTEP(T16,16) VSTEP(T17,17) VSTEP(T18,18) VSTEP(T19,19)
        VSTEP(T20,20) VSTEP(T21,21) VSTEP(T22,22) VSTEP(T23,23)
        VSTEP(T24,24) VSTEP(T25,25) VSTEP(T26,26) VSTEP(T27,27)
        VSTEP(T28,28) VSTEP(T29,29) VSTEP(T30,30) VSTEP(T31,31)
#undef VSTEP
        float m = fmaxf(fmaxf(mv.x, mv.y), fmaxf(mv.z, mv.w));
        m = fmaxf(m, __shfl_xor(m, 32));     // combine i-halves
        if (h0) {
            float v = m + ft;
            fvb[p ^ 1][j] = v;
            fv_all[(size_t)t * 256 + j] = v;
        }
        BAR_LGKM();
    }
}

// ---------------- 256x256 transpose of trans ----------------
__global__ __launch_bounds__(256) void transpose_kernel(
    const float* __restrict__ in, float* __restrict__ out)
{
    __shared__ float tile[16][17];
    int bx = blockIdx.x & 15, by = blockIdx.x >> 4;
    int tx = threadIdx.x & 15, ty = threadIdx.x >> 4;
    tile[ty][tx] = in[(size_t)(by * 16 + ty) * 256 + bx * 16 + tx];
    __syncthreads();
    out[(size_t)(bx * 16 + ty) * 256 + by * 16 + tx] = tile[tx][ty];
}

// ---------------- backpointers, fully parallel (coalesced via transT) ----------------
__global__ __launch_bounds__(256) void bp_kernel(
    const float* __restrict__ fv_all, const float* __restrict__ transT,
    unsigned char* __restrict__ bp)
{
    __shared__ float fp[256];
    int t = blockIdx.x;
    int j = threadIdx.x;
    fp[j] = (t == 0) ? ((j == START_TAG) ? 0.f : NEGV)
                     : fv_all[(size_t)(t - 1) * 256 + j];
    __syncthreads();
    float m = -1e30f; int mi = 0;
#pragma unroll 4
    for (int i = 0; i < 256; ++i) {
        float s = fp[i] + transT[(size_t)i * 256 + j];
        if (s > m) { m = s; mi = i; }   // strict > : first max index (jnp.argmax)
    }
    bp[(size_t)t * 256 + j] = (unsigned char)mi;
}

// ---------------- segmented backtrace ----------------
__global__ __launch_bounds__(256) void evol_kernel(
    const unsigned char* __restrict__ bp, unsigned char* __restrict__ evol)
{
    __shared__ unsigned char tm[256];
    __shared__ unsigned char row[256];
    int s = blockIdx.x;
    int tid = threadIdx.x;
    int t_top = s * 64 + 63;
    tm[tid] = (unsigned char)tid;
    evol[(size_t)t_top * 256 + tid] = (unsigned char)tid;
    __syncthreads();
    for (int t = t_top - 1; t >= s * 64; --t) {
        row[tid] = bp[(size_t)(t + 1) * 256 + tid];
        __syncthreads();
        unsigned char nt = row[tm[tid]];
        tm[tid] = nt;
        evol[(size_t)t * 256 + tid] = nt;
        __syncthreads();
    }
}

__global__ __launch_bounds__(256) void finalize_kernel(
    const float* __restrict__ fv_all, const float* __restrict__ trans,
    const unsigned char* __restrict__ bp, const unsigned char* __restrict__ evol,
    float* __restrict__ out)
{
    __shared__ float term[256];
    __shared__ unsigned char top[64];
    int tid = threadIdx.x;
    term[tid] = fv_all[(size_t)(T_LEN - 1) * 256 + tid] + trans[STOP_TAG * 256 + tid];
    __syncthreads();
    if (tid == 0) {
        float m = term[0]; int best = 0;
        for (int i = 1; i < 256; ++i) if (term[i] > m) { m = term[i]; best = i; }
        out[0] = m;
        int tag = best;
        top[63] = (unsigned char)tag;
        for (int s2 = 63; s2 >= 1; --s2) {
            int tb = s2 * 64;
            int pb = evol[(size_t)tb * 256 + tag];
            tag = bp[(size_t)tb * 256 + pb];
            top[s2 - 1] = (unsigned char)tag;
        }
    }
    __syncthreads();
    for (int t = tid; t < T_LEN; t += 256)
        out[1 + t] = (float)evol[(size_t)t * 256 + top[t >> 6]];
}

// ---------------- host launcher ----------------
extern "C" void kernel_launch(void* const* d_in, const int* in_sizes, int n_in,
                              void* d_out, int out_size, void* d_ws, size_t ws_size,
                              hipStream_t stream)
{
    const int*   src     = (const int*)d_in[0];
    const float* emb     = (const float*)d_in[2];
    const float* W_ih_f  = (const float*)d_in[3];
    const float* W_hh_f  = (const float*)d_in[4];
    const float* b_ih_f  = (const float*)d_in[5];
    const float* b_hh_f  = (const float*)d_in[6];
    const float* W_ih_b  = (const float*)d_in[7];
    const float* W_hh_b  = (const float*)d_in[8];
    const float* b_ih_b  = (const float*)d_in[9];
    const float* b_hh_b  = (const float*)d_in[10];
    const float* W_tag   = (const float*)d_in[11];
    const float* b_tag   = (const float*)d_in[12];
    const float* trans   = (const float*)d_in[13];
    float* out = (float*)d_out;

    char* w = (char*)d_ws;
    unsigned long long* pub = (unsigned long long*)w;   // 2 dir x 2 slot x 512 x 8B = 16 KB
    size_t off = 32768;
    float* PE_f = (float*)(w + off); off += (size_t)NVOC * G4 * 4;
    float* PE_b = (float*)(w + off); off += (size_t)NVOC * G4 * 4;
    float* H    = (float*)(w + off); off += (size_t)T_LEN * 1024 * 4;
    float* feats= (float*)(w + off); off += (size_t)T_LEN * 256 * 4;
    float* fv   = (float*)(w + off); off += (size_t)T_LEN * 256 * 4;
    float* transT = (float*)(w + off); off += (size_t)256 * 256 * 4;
    unsigned char* bp   = (unsigned char*)(w + off); off += (size_t)T_LEN * 256;
    unsigned char* evol = (unsigned char*)(w + off); off += (size_t)T_LEN * 256;

    hipMemsetAsync(pub, 0, 16384, stream);

    gemm_abt<<<dim3(NVOC / 64, G4 / 64), 256, 0, stream>>>(emb, W_ih_f, b_ih_f, b_hh_f, PE_f, NVOC, G4, EMBD);
    gemm_abt<<<dim3(NVOC / 64, G4 / 64), 256, 0, stream>>>(emb, W_ih_b, b_ih_b, b_hh_b, PE_b, NVOC, G4, EMBD);
    transpose_kernel<<<256, 256, 0, stream>>>(trans, transT);

    lstm_kernel<<<64, 512, 0, stream>>>(src, PE_f, PE_b, W_hh_f, W_hh_b, H, pub);

    gemm_abt<<<dim3(T_LEN / 64, 256 / 64), 256, 0, stream>>>(H, W_tag, b_tag, nullptr, feats, T_LEN, 256, 1024);

    viterbi_fwd_kernel<<<1, 512, 0, stream>>>(feats, trans, fv);
    bp_kernel<<<T_LEN, 256, 0, stream>>>(fv, transT, bp);
    evol_kernel<<<T_LEN / 64, 256, 0, stream>>>(bp, evol);
    finalize_kernel<<<1, 256, 0, stream>>>(fv, trans, bp, evol, out);
}